// Round 4
// baseline (217.481 us; speedup 1.0000x reference)
//
#include <hip/hip_runtime.h>

typedef short bf16x8 __attribute__((ext_vector_type(8)));   // 8 bf16 in 4 VGPRs
typedef float f32x4  __attribute__((ext_vector_type(4)));
typedef int   i32x4  __attribute__((ext_vector_type(4)));
typedef unsigned int u32x2 __attribute__((ext_vector_type(2)));

#define DEV static __device__ __forceinline__

DEV float bfu_to_f(unsigned short s) { return __builtin_bit_cast(float, (unsigned int)s << 16); }
DEV unsigned short f_to_bf(float f) {                 // RNE fp32 -> bf16
  unsigned int u = __builtin_bit_cast(unsigned int, f);
  u += 0x7fffu + ((u >> 16) & 1u);
  return (unsigned short)(u >> 16);
}
DEV unsigned int pack_bf_rne(float lo, float hi) {
  return (unsigned int)f_to_bf(lo) | ((unsigned int)f_to_bf(hi) << 16);
}
// RTZ pack of two f32 -> (bf16(hi)<<16)|bf16(lo): one v_perm_b32
DEV unsigned int pack_bf_rtz(float lo, float hi) {
#if __has_builtin(__builtin_amdgcn_perm)
  return __builtin_amdgcn_perm(__builtin_bit_cast(unsigned int, hi),
                               __builtin_bit_cast(unsigned int, lo), 0x07060302u);
#else
  return (__builtin_bit_cast(unsigned int, hi) & 0xffff0000u) |
         (__builtin_bit_cast(unsigned int, lo) >> 16);
#endif
}

// dtype discriminator: adj[0][0] == 1.0 exactly. fp32 word0 == 0x3F800000;
// bf16 word0 low halfword = 0x3F80 != 0 -> never equal.
DEV bool detect_f32(const void* adj) { return ((const float*)adj)[0] == 1.0f; }

template<bool F32> DEV float ldS(const void* p, size_t i) {
  if constexpr (F32) return ((const float*)p)[i];
  else               return bfu_to_f(((const unsigned short*)p)[i]);
}
template<bool F32> DEV void ld8f(const void* p, size_t i, float* o) {
  if constexpr (F32) {
    const float* f = (const float*)p + i;
    f32x4 a = *(const f32x4*)f, b = *(const f32x4*)(f + 4);
    o[0]=a[0]; o[1]=a[1]; o[2]=a[2]; o[3]=a[3];
    o[4]=b[0]; o[5]=b[1]; o[6]=b[2]; o[7]=b[3];
  } else {
    i32x4 w = *(const i32x4*)((const unsigned short*)p + i);
#pragma unroll
    for (int k = 0; k < 4; ++k) {
      unsigned int u = (unsigned int)w[k];
      o[2*k]   = __builtin_bit_cast(float, u << 16);
      o[2*k+1] = __builtin_bit_cast(float, u & 0xffff0000u);
    }
  }
}
template<bool F32> DEV bf16x8 ldfrag(const void* p, size_t i) {
  if constexpr (F32) {
    float o[8]; ld8f<true>(p, i, o);
    union { bf16x8 v; unsigned short u[8]; } r;
#pragma unroll
    for (int k = 0; k < 8; ++k) r.u[k] = f_to_bf(o[k]);
    return r.v;
  } else {
    return __builtin_bit_cast(bf16x8, *(const i32x4*)((const unsigned short*)p + i));
  }
}

// ---------------- Kernel 0: adj fp32 -> bf16 (f32 path only; no-op for bf16 inputs) ----
__global__ __launch_bounds__(256) void k_prep(const void* __restrict__ adj,
                                              unsigned short* __restrict__ adjb) {
  if (!detect_f32(adj)) return;
  const float* a = (const float*)adj;
  const size_t i0 = ((size_t)blockIdx.x * 256 + threadIdx.x) * 8;   // 2048 blocks * 256 * 8 = 4M
  f32x4 v0 = *(const f32x4*)(a + i0), v1 = *(const f32x4*)(a + i0 + 4);
  i32x4 o;
  o[0] = (int)pack_bf_rne(v0[0], v0[1]);
  o[1] = (int)pack_bf_rne(v0[2], v0[3]);
  o[2] = (int)pack_bf_rne(v1[0], v1[1]);
  o[3] = (int)pack_bf_rne(v1[2], v1[3]);
  *(i32x4*)(adjb + i0) = o;
}

// ---------------- Kernel 1: hT[bh*32+d][n] = (x @ W^T)[b,n,hh*32+d]  (bf16) ----------
template<bool F32> DEV void k_h_body(const void* __restrict__ x, const void* __restrict__ W,
                                     unsigned short* __restrict__ hT) {
  const int lane = threadIdx.x & 63, wave = threadIdx.x >> 6;
  const int tile = blockIdx.x * 4 + wave;      // 8192 tiles = 1024 rt x 8 ct
  const int rt = tile >> 3, ct = tile & 7;
  const int m = lane & 15, q = lane >> 4;
  const size_t xo = (size_t)(rt * 16 + m) * 128 + q * 8;
  const size_t wo = (size_t)(ct * 16 + m) * 128 + q * 8;
  f32x4 acc = {0.f, 0.f, 0.f, 0.f};
#pragma unroll
  for (int k = 0; k < 4; ++k)
    acc = __builtin_amdgcn_mfma_f32_16x16x32_bf16(ldfrag<F32>(x, xo + k * 32),
                                                  ldfrag<F32>(W, wo + k * 32), acc, 0, 0, 0);
  // C: col = ct*16+m (channel), rows n = rt*16 + q*4 + r. Transposed store: 4 consecutive n.
  const int c = ct * 16 + m, hh = c >> 5, dloc = c & 31;
  const int b = rt >> 7, nl0 = (rt & 127) * 16 + q * 4;
  unsigned short* tp = hT + ((size_t)((b * 4 + hh) * 32 + dloc)) * 2048 + nl0;
  u32x2 w2; w2[0] = pack_bf_rne(acc[0], acc[1]); w2[1] = pack_bf_rne(acc[2], acc[3]);
  *(u32x2*)tp = w2;
}
__global__ __launch_bounds__(256) void k_h(const void* x, const void* W,
                                           unsigned short* hT, const void* adj) {
  if (detect_f32(adj)) k_h_body<true>(x, W, hT); else k_h_body<false>(x, W, hT);
}

// ---------------- Kernel 1b: src/dst projections (coalesced hT column reads) ----------
template<bool F32> DEV void k_sd_body(const unsigned short* __restrict__ hT,
                                      const void* __restrict__ a_src, const void* __restrict__ a_dst,
                                      float* __restrict__ srcv, float* __restrict__ dstv) {
  const int t = blockIdx.x * 256 + threadIdx.x;      // (bh, n), n fastest
  const int n = t & 2047, bh = t >> 11, hh = bh & 3;
  const unsigned short* col = hT + (size_t)bh * 32 * 2048 + n;
  float s = 0.f, d = 0.f;
#pragma unroll
  for (int dd = 0; dd < 32; ++dd) {
    const float v = bfu_to_f(col[(size_t)dd * 2048]);
    s += v * ldS<F32>(a_src, hh * 32 + dd);
    d += v * ldS<F32>(a_dst, hh * 32 + dd);
  }
  srcv[t] = s; dstv[t] = d;
}
__global__ __launch_bounds__(256) void k_sd(const unsigned short* hT, const void* a_src,
                                            const void* a_dst, float* srcv, float* dstv,
                                            const void* adj) {
  if (detect_f32(adj)) k_sd_body<true>(hT, a_src, a_dst, srcv, dstv);
  else                 k_sd_body<false>(hT, a_src, a_dst, srcv, dstv);
}

// ---------------- Kernel 2: barrier-free flash GAT attention ----------------
// Per wave: one (bh, 16-row i-tile), full j sweep. attn_ij = A_ij*exp(leaky(src_i+dst_j))/den_i.
// Computes (PV)^T via MFMA: A-operand = V^T (direct 16B loads from hT), B-operand = P^T
// (the scores this lane computes: i = lane&15, j = (lane>>4)*8 + jj). No LDS, no barriers.
// AMODE: 0 = adj fp32 direct, 1 = adj bf16 (native or pre-converted).
template<int AMODE> DEV void k_attn_body(const void* __restrict__ adjv,
                                         const unsigned short* __restrict__ hT,
                                         const float* __restrict__ srcv,
                                         const float* __restrict__ dstv,
                                         unsigned short* __restrict__ ao) {
  const int tid = threadIdx.x, lane = tid & 63, wave = tid >> 6;
  const int task = blockIdx.x * 4 + wave;          // 4096 tasks
  const int bh = task & 31, i16 = task >> 5;       // bh fast: adjacent blocks share adj rows
  const int b = bh >> 2, hh = bh & 3;
  const int m = lane & 15, q = lane >> 4;
  const int nl = i16 * 16 + m;                     // this lane's i-row (graph node index)

  const float src_i = srcv[bh * 2048 + nl];
  const float* dp = dstv + bh * 2048 + q * 8;
  const unsigned short* vp0 = hT + ((size_t)bh * 32 + m) * 2048 + q * 8;        // V^T rows d=m
  const unsigned short* vp1 = vp0 + (size_t)16 * 2048;                          // d=m+16
  const unsigned short* apb = (const unsigned short*)adjv + (size_t)nl * 2048 + q * 8;
  const float*          apf = (const float*)adjv + (size_t)nl * 2048 + q * 8;

  f32x4 acc0 = {0.f,0.f,0.f,0.f}, acc1 = {0.f,0.f,0.f,0.f};
  float den0 = 0.f, den1 = 0.f;

#pragma unroll 2
  for (int jt = 0; jt < 2048; jt += 32) {
    // issue all loads up front
    f32x4 dv0 = *(const f32x4*)(dp + jt);
    f32x4 dv1 = *(const f32x4*)(dp + jt + 4);
    bf16x8 A0 = __builtin_bit_cast(bf16x8, *(const i32x4*)(vp0 + jt));
    bf16x8 A1 = __builtin_bit_cast(bf16x8, *(const i32x4*)(vp1 + jt));
    float a[8];
    if constexpr (AMODE == 1) {
      i32x4 av = *(const i32x4*)(apb + jt);
#pragma unroll
      for (int k = 0; k < 4; ++k) {
        unsigned int w = (unsigned int)av[k];
        a[2*k]   = __builtin_bit_cast(float, w << 16);
        a[2*k+1] = __builtin_bit_cast(float, w & 0xffff0000u);
      }
    } else {
      f32x4 av0 = *(const f32x4*)(apf + jt);
      f32x4 av1 = *(const f32x4*)(apf + jt + 4);
#pragma unroll
      for (int k = 0; k < 4; ++k) { a[k] = av0[k]; a[4+k] = av1[k]; }
    }
    float p[8];
#pragma unroll
    for (int pp = 0; pp < 8; ++pp) {
      const float dj = (pp < 4) ? dv0[pp] : dv1[pp - 4];
      const float s  = src_i + dj;
      const float l  = fmaxf(s, 0.f) + 0.2f * fminf(s, 0.f);   // leaky, no branches
      p[pp] = a[pp] * __expf(l);                               // a==0 -> p==0 exactly
    }
    den0 += p[0] + p[2] + p[4] + p[6];
    den1 += p[1] + p[3] + p[5] + p[7];
    i32x4 pk4;
    pk4[0] = (int)pack_bf_rtz(p[0], p[1]);
    pk4[1] = (int)pack_bf_rtz(p[2], p[3]);
    pk4[2] = (int)pack_bf_rtz(p[4], p[5]);
    pk4[3] = (int)pack_bf_rtz(p[6], p[7]);
    const bf16x8 pk = __builtin_bit_cast(bf16x8, pk4);
    acc0 = __builtin_amdgcn_mfma_f32_16x16x32_bf16(A0, pk, acc0, 0, 0, 0);
    acc1 = __builtin_amdgcn_mfma_f32_16x16x32_bf16(A1, pk, acc1, 0, 0, 0);
  }

  float den = den0 + den1;
  den += __shfl_xor(den, 16, 64);                  // row i=m's partials live on q=0..3
  den += __shfl_xor(den, 32, 64);
  const float inv = 1.f / fmaxf(den, 1e-20f);

  // D layout: col = lane&15 = i (= m), row = q*4+r = d. Lane writes 4+4 contiguous channels.
  unsigned short* op = ao + ((size_t)(b * 2048) + nl) * 128 + hh * 32 + q * 4;
  u32x2 w0, w1;
  w0[0] = pack_bf_rne(acc0[0] * inv, acc0[1] * inv);
  w0[1] = pack_bf_rne(acc0[2] * inv, acc0[3] * inv);
  w1[0] = pack_bf_rne(acc1[0] * inv, acc1[1] * inv);
  w1[1] = pack_bf_rne(acc1[2] * inv, acc1[3] * inv);
  *(u32x2*)op        = w0;
  *(u32x2*)(op + 16) = w1;
}
__global__ __launch_bounds__(256) void k_attn(const void* adj, const unsigned short* adjb_ws,
                                              const unsigned short* hT, const float* srcv,
                                              const float* dstv, unsigned short* ao,
                                              int have_bf_ws) {
  if (detect_f32(adj)) {
    if (have_bf_ws) k_attn_body<1>(adjb_ws, hT, srcv, dstv, ao);
    else            k_attn_body<0>(adj,     hT, srcv, dstv, ao);
  } else {
    k_attn_body<1>(adj, hT, srcv, dstv, ao);
  }
}

// ---------------- Kernel 3: y = LN(ao @ Wo^T + bo + x) ----------------
template<bool F32> DEV void k_out_body(const unsigned short* __restrict__ ao,
                                       const void* __restrict__ Wo, const void* __restrict__ bo,
                                       const void* __restrict__ x, const void* __restrict__ gamma,
                                       const void* __restrict__ beta, void* __restrict__ out) {
  __shared__ __align__(16) float y_s[16][132];
  const int tid = threadIdx.x, lane = tid & 63, wave = tid >> 6;
  const int m = lane & 15, q = lane >> 4;
  const int rbase = blockIdx.x * 16;
  bf16x8 af[4];
#pragma unroll
  for (int k = 0; k < 4; ++k)
    af[k] = ldfrag<false>(ao, ((size_t)(rbase + m)) * 128 + q * 8 + k * 32);
  f32x4 acc[2] = {{0.f,0.f,0.f,0.f},{0.f,0.f,0.f,0.f}};
#pragma unroll
  for (int ct = 0; ct < 2; ++ct) {
    const size_t wrow = (size_t)(wave * 32 + ct * 16 + m) * 128 + q * 8;
#pragma unroll
    for (int k = 0; k < 4; ++k)
      acc[ct] = __builtin_amdgcn_mfma_f32_16x16x32_bf16(af[k], ldfrag<F32>(Wo, wrow + k * 32),
                                                        acc[ct], 0, 0, 0);
  }
#pragma unroll
  for (int ct = 0; ct < 2; ++ct) {
    const int c = wave * 32 + ct * 16 + m;
    const float bov = ldS<F32>(bo, c);
#pragma unroll
    for (int r = 0; r < 4; ++r) {
      const int row = q * 4 + r;
      y_s[row][c] = acc[ct][r] + bov + ldS<F32>(x, (size_t)(rbase + row) * 128 + c);
    }
  }
  __syncthreads();
  const int r = tid >> 4, c16 = tid & 15;
  float vals[8], sum = 0.f, sq = 0.f;
#pragma unroll
  for (int k = 0; k < 8; ++k) {
    const float v = y_s[r][c16 * 8 + k];
    vals[k] = v; sum += v; sq += v * v;
  }
#pragma unroll
  for (int msk = 1; msk < 16; msk <<= 1) {
    sum += __shfl_xor(sum, msk, 16);
    sq  += __shfl_xor(sq,  msk, 16);
  }
  const float mu  = sum * (1.f / 128.f);
  const float var = fmaxf(sq * (1.f / 128.f) - mu * mu, 0.f);
  const float rstd = rsqrtf(var + 1e-5f);
  float o[8];
#pragma unroll
  for (int k = 0; k < 8; ++k) {
    const int c = c16 * 8 + k;
    o[k] = (vals[k] - mu) * rstd * ldS<F32>(gamma, c) + ldS<F32>(beta, c);
  }
  const size_t obase = (size_t)(rbase + r) * 128 + c16 * 8;
  if constexpr (F32) {
    float* op = (float*)out + obase;
    f32x4 w0 = {o[0],o[1],o[2],o[3]}, w1 = {o[4],o[5],o[6],o[7]};
    *(f32x4*)op = w0; *(f32x4*)(op + 4) = w1;
  } else {
    union { unsigned short u[8]; i32x4 v; } ob;
#pragma unroll
    for (int k = 0; k < 8; ++k) ob.u[k] = f_to_bf(o[k]);
    *(i32x4*)((unsigned short*)out + obase) = ob.v;
  }
}
__global__ __launch_bounds__(256) void k_out(const unsigned short* ao, const void* Wo,
                                             const void* bo, const void* x, const void* gamma,
                                             const void* beta, void* out, const void* adj) {
  if (detect_f32(adj)) k_out_body<true>(ao, Wo, bo, x, gamma, beta, out);
  else                 k_out_body<false>(ao, Wo, bo, x, gamma, beta, out);
}

// ---------------- launch ----------------
extern "C" void kernel_launch(void* const* d_in, const int* in_sizes, int n_in,
                              void* d_out, int out_size, void* d_ws, size_t ws_size,
                              hipStream_t stream) {
  const void* x     = d_in[0];
  const void* adj   = d_in[1];
  const void* W     = d_in[2];
  const void* a_src = d_in[3];
  const void* a_dst = d_in[4];
  const void* Wo    = d_in[5];
  const void* bo    = d_in[6];
  const void* gamma = d_in[7];
  const void* beta  = d_in[8];

  char* ws = (char*)d_ws;
  unsigned short* hT_ws  = (unsigned short*)ws;                       // 4.19 MB
  unsigned short* ao_ws  = (unsigned short*)(ws + 4194304);           // 4.19 MB
  float*          src_ws = (float*)(ws + 8388608);                    // 256 KB
  float*          dst_ws = (float*)(ws + 8650752);                    // 256 KB
  unsigned short* adjb   = (unsigned short*)(ws + 8912896);           // 8.39 MB (optional)
  const int have_bf_ws = (ws_size >= 17301504u) ? 1 : 0;

  if (have_bf_ws) k_prep<<<2048, 256, 0, stream>>>(adj, adjb);
  k_h   <<<2048, 256, 0, stream>>>(x, W, hT_ws, adj);
  k_sd  <<<256,  256, 0, stream>>>(hT_ws, a_src, a_dst, src_ws, dst_ws, adj);
  k_attn<<<1024, 256, 0, stream>>>(adj, adjb, hT_ws, src_ws, dst_ws, ao_ws, have_bf_ws);
  k_out <<<1024, 256, 0, stream>>>(ao_ws, Wo, bo, x, gamma, beta, d_out, adj);
}